// Round 4
// baseline (650.915 us; speedup 1.0000x reference)
//
#include <hip/hip_runtime.h>
#include <hip/hip_cooperative_groups.h>

namespace cg = cooperative_groups;

// out[b] = M[b] @ X[b] + bias2, where (X = x_in[b] as [192,16384])
//   G[b]  = X X^T (Gram) ; Wq'=w_q@w_split etc.; Wo2=w_out@w_proj; bias2=w_out@b_proj
//   Tk = Wk' G ; qn[d]=sqrt(Wq'[d] G Wq'[d]^T) ; kn[cc]=sqrt(Tk[cc]·Wk'[cc])
//   A = softmax_rows(Tk Wq'^T / (kn ⊗ qn)) ; M = Wo2 (A Wv')
// Heavy phases (Gram, final GEMM) use bf16 MFMA 16x16x32 with fp32 accum.
// Middle chain (gsum/tkqn/attn/m) fused into ONE cooperative kernel: it is
// ~0.6 GFLOP spread over 4 launches + HBM round-trips (~190 us = 63% of total).

static constexpr int B_ = 8;
static constexpr int C_ = 192;
static constexpr int N_ = 16384;
static constexpr int CC2 = C_ * C_;
static constexpr int NCHUNK = 32;

using u16x8 = __attribute__((ext_vector_type(8))) unsigned short;
using bf16x8 = __attribute__((ext_vector_type(8))) __bf16;
using f32x4 = __attribute__((ext_vector_type(4))) float;
using uint32x4 = __attribute__((ext_vector_type(4))) unsigned int;

__device__ __forceinline__ unsigned short f2bf(float f) {
  unsigned int u = __builtin_bit_cast(unsigned int, f);
  u += 0x7FFFu + ((u >> 16) & 1u);   // RNE
  return (unsigned short)(u >> 16);
}

// packed f32x2 -> bf16x2 (compiler emits v_cvt_pk_bf16_f32; RNE)
__device__ __forceinline__ unsigned int pkbf(float lo, float hi) {
  unsigned short a = __builtin_bit_cast(unsigned short, (__bf16)lo);
  unsigned short b = __builtin_bit_cast(unsigned short, (__bf16)hi);
  return (unsigned int)a | ((unsigned int)b << 16);
}

__device__ __forceinline__ float f4get(const float4& v, int e) {
  return (e == 0) ? v.x : (e == 1) ? v.y : (e == 2) ? v.z : v.w;
}

__device__ __forceinline__ f32x4 mfma16(u16x8 a, u16x8 b, f32x4 c) {
  return __builtin_amdgcn_mfma_f32_16x16x32_bf16(
      __builtin_bit_cast(bf16x8, a), __builtin_bit_cast(bf16x8, b), c, 0, 0, 0);
}

// ---------------- fold weights ----------------
__global__ void fold_kernel(const float* __restrict__ wsplit, const float* __restrict__ wq,
                            const float* __restrict__ wk, const float* __restrict__ wv,
                            const float* __restrict__ wproj, const float* __restrict__ bproj,
                            const float* __restrict__ wout,
                            float* __restrict__ Wq, float* __restrict__ WqT,
                            float* __restrict__ Wk, float* __restrict__ Wv,
                            float* __restrict__ Wo2, float* __restrict__ bias2) {
  int idx = blockIdx.x * 256 + threadIdx.x;
  if (idx < C_) {
    float s = 0.f;
    for (int c = 0; c < C_; ++c) s += wout[idx * C_ + c] * bproj[c];
    bias2[idx] = s;
  }
  if (idx >= 4 * CC2) return;
  int which = idx / CC2;
  int rem = idx % CC2;
  int o = rem / C_, c = rem % C_;
  const float* A = (which == 0) ? wq : (which == 1) ? wk : (which == 2) ? wv : wout;
  const float* Bm = (which == 3) ? wproj : wsplit;
  float s = 0.f;
  for (int e = 0; e < C_; ++e) s += A[o * C_ + e] * Bm[e * C_ + c];
  if (which == 0) { Wq[rem] = s; WqT[c * C_ + o] = s; }
  else if (which == 1) Wk[rem] = s;
  else if (which == 2) Wv[rem] = s;
  else Wo2[rem] = s;
}

// ---------------- Gram: row-split x2 for 2 blocks/CU, double-buffered pipeline ----------
// grid (32 k-chunks, 2 row-halves, 8 batches) = 512 blocks, 384 thr (6 waves).
// (gram4's single-pass full-tile variant regressed: 256 blocks = 1 block/CU left
//  barrier drains uncovered; xin is L3-resident so the duplicate read is cheap.)
template <bool ATOMIC>
__global__ __launch_bounds__(384) void gram3_kernel(const float* __restrict__ xin,
                                                    float* __restrict__ dst) {
  const int b = blockIdx.z, half = blockIdx.y, ch = blockIdx.x;
  const int k0 = ch * 512;
  __shared__ unsigned short Xs[2][C_][72];         // dbuf, pitch 72 (2-way = free)
  const int tid = threadIdx.x;
  const int wv = tid >> 6;                         // 0..5
  const int lane = tid & 63;
  const int ln = lane & 15, mq = lane >> 4;
  const int arow0 = half * 96 + wv * 16;           // this wave's 16 G-rows
  const int cbase = tid >> 4;                      // 0..23
  const int k4 = tid & 15;
  const float* xb = xin + (size_t)b * C_ * N_;

  f32x4 acc[12];
#pragma unroll
  for (int j = 0; j < 12; ++j) acc[j] = (f32x4)0.0f;

  float4 ld[8];
  auto load_stage = [&](int kbase) {
#pragma unroll
    for (int j = 0; j < 8; ++j)
      ld[j] = *(const float4*)(xb + (size_t)(j * 24 + cbase) * N_ + kbase + k4 * 4);
  };
  auto write_stage = [&](int buf) {
#pragma unroll
    for (int j = 0; j < 8; ++j) {
      uint2 pk;
      pk.x = pkbf(ld[j].x, ld[j].y);
      pk.y = pkbf(ld[j].z, ld[j].w);
      *(uint2*)&Xs[buf][j * 24 + cbase][k4 * 4] = pk;    // ds_write_b64
    }
  };

  load_stage(k0);
  write_stage(0);
  __syncthreads();
  for (int s = 0; s < 8; ++s) {                    // 8 stages of 64 k
    if (s < 7) load_stage(k0 + (s + 1) * 64);      // prefetch overlaps MFMA
    const int cb = s & 1;
#pragma unroll
    for (int ks = 0; ks < 2; ++ks) {
      const int kk = ks * 32 + mq * 8;
      u16x8 a0 = *(const u16x8*)&Xs[cb][arow0 + ln][kk];
#pragma unroll
      for (int ct = 0; ct < 12; ++ct) {
        u16x8 bf = *(const u16x8*)&Xs[cb][ct * 16 + ln][kk];
        acc[ct] = mfma16(a0, bf, acc[ct]);
      }
    }
    if (s < 7) {
      write_stage(cb ^ 1);   // safe: cb^1 last read a full barrier ago
      __syncthreads();
    }
  }
  float* out = ATOMIC ? dst + (size_t)b * CC2
                      : dst + ((size_t)b * NCHUNK + ch) * CC2;
#pragma unroll
  for (int ct = 0; ct < 12; ++ct)
#pragma unroll
    for (int r = 0; r < 4; ++r) {
      int row = arow0 + mq * 4 + r;
      int col = ct * 16 + ln;
      if (ATOMIC) atomicAdd(&out[row * C_ + col], acc[ct][r]);
      else out[row * C_ + col] = acc[ct][r];
    }
}

// ---------------- fused middle: gsum + tkqn + attn_av + m, one cooperative kernel ----
// 512 blocks x 256 thr (2 blocks/CU, all-resident), 3 grid.sync() phase barriers.
// Math is bit-identical fp32, same op order as the 4 separate kernels it replaces.
template <bool SUMP>
__global__ __launch_bounds__(256) void middle_kernel(
    const float* __restrict__ P, float* __restrict__ G,
    const float* __restrict__ Wk, const float* __restrict__ Wq,
    const float* __restrict__ WqT, const float* __restrict__ Wv,
    const float* __restrict__ Wo2, float* __restrict__ Tk,
    float* __restrict__ qn, float* __restrict__ Tv, float* __restrict__ Mw) {
  cg::grid_group grid = cg::this_grid();
  const int blk = blockIdx.x;                      // 0..511
  const int t = threadIdx.x;                       // 0..255
  __shared__ float tkrow[C_];
  __shared__ float arow[C_];
  __shared__ float red[256];

  // ---- phase 0: G = sum of 32 partials (the old gsum) ----
  if (SUMP) {
    for (int idx4 = blk * 256 + t; idx4 < B_ * CC2 / 4; idx4 += 512 * 256) {
      int b = idx4 / (CC2 / 4);
      int jj = idx4 % (CC2 / 4);
      const float* base = P + (size_t)b * NCHUNK * CC2 + jj * 4;
      float4 s = {0.f, 0.f, 0.f, 0.f};
#pragma unroll
      for (int ch = 0; ch < NCHUNK; ++ch) {
        float4 v = *(const float4*)(base + (size_t)ch * CC2);
        s.x += v.x; s.y += v.y; s.z += v.z; s.w += v.w;
      }
      *(float4*)(G + (size_t)b * CC2 + jj * 4) = s;
    }
    __threadfence();
    grid.sync();
  }

  // ---- phase 1: Tk rows + qn (the old tkqn). 1536 (b,d) tasks, 3 per block ----
  for (int r = 0; r < 3; ++r) {
    const int task = blk + 512 * r;
    const int b = task / C_, d = task % C_;
    const float* Gb = G + (size_t)b * CC2;
    float sq = 0.f;
    if (t < C_) {
      float sk = 0.f;
      for (int c = 0; c < C_; ++c) {
        float g = Gb[c * C_ + t];
        sk += Wk[d * C_ + c] * g;
        sq += Wq[d * C_ + c] * g;
      }
      Tk[((size_t)b * C_ + d) * C_ + t] = sk;
    }
    red[t] = (t < C_) ? sq * Wq[d * C_ + t] : 0.f;
    __syncthreads();
    for (int st = 128; st > 0; st >>= 1) {
      if (t < st) red[t] += red[t + st];
      __syncthreads();
    }
    if (t == 0) qn[b * C_ + d] = fmaxf(sqrtf(fmaxf(red[0], 0.f)), 1e-12f);
    __syncthreads();
  }
  __threadfence();
  grid.sync();

  // ---- phase 2: kn + logits + softmax + Tv (the old attn_av). 3 tasks/block ----
  for (int r = 0; r < 3; ++r) {
    const int task = blk + 512 * r;
    const int b = task / C_, cc = task % C_;
    float tkv = 0.f;
    if (t < C_) {
      tkv = Tk[((size_t)b * C_ + cc) * C_ + t];
      tkrow[t] = tkv;
    }
    red[t] = (t < C_) ? tkv * Wk[cc * C_ + t] : 0.f;
    __syncthreads();
    for (int st = 128; st > 0; st >>= 1) {
      if (t < st) red[t] += red[t + st];
      __syncthreads();
    }
    float knv = fmaxf(sqrtf(fmaxf(red[0], 0.f)), 1e-12f);
    __syncthreads();
    float lg = -1e30f;
    if (t < C_) {
      float s = 0.f;
      for (int c = 0; c < C_; ++c) s += tkrow[c] * WqT[c * C_ + t];
      lg = s / (knv * qn[b * C_ + t]);
    }
    red[t] = lg;
    __syncthreads();
    for (int st = 128; st > 0; st >>= 1) {
      if (t < st) red[t] = fmaxf(red[t], red[t + st]);
      __syncthreads();
    }
    float mx = red[0];
    __syncthreads();
    float e = (t < C_) ? expf(lg - mx) : 0.f;
    red[t] = e;
    __syncthreads();
    for (int st = 128; st > 0; st >>= 1) {
      if (t < st) red[t] += red[t + st];
      __syncthreads();
    }
    float a = e / red[0];
    __syncthreads();
    if (t < C_) arow[t] = a;
    __syncthreads();
    if (t < C_) {
      float sv = 0.f;
      for (int c = 0; c < C_; ++c) sv += arow[c] * Wv[c * C_ + t];
      Tv[((size_t)b * C_ + cc) * C_ + t] = sv;
    }
    __syncthreads();
  }
  __threadfence();
  grid.sync();

  // ---- phase 3: M = Wo2 @ Tv (the old m_kernel), grid-stride ----
  for (int idx = blk * 256 + t; idx < B_ * CC2; idx += 512 * 256) {
    int b = idx / CC2;
    int rc = idx % CC2;
    int i = rc / C_, j = rc % C_;
    float s = 0.f;
    for (int c = 0; c < C_; ++c) s += Wo2[i * C_ + c] * Tv[((size_t)b * C_ + c) * C_ + j];
    Mw[idx] = s;
  }
}

// ---------------- final: out[b] = M[b] @ X[b] + bias2, bf16 MFMA ----------------
// v3b (measured 59.4 us): 64-px blocks, 24 KB LDS, 2-section register-prefetch,
// packed b64 LDS writes, swizzle key (p>>1)&7, __launch_bounds__(384,4) (no spill).
__global__ __launch_bounds__(384, 4) void final3_kernel(const float* __restrict__ xin,
                                                        const float* __restrict__ Mw,
                                                        const float* __restrict__ bias2,
                                                        float* __restrict__ out) {
  const int b = blockIdx.y;
  const int p0 = blockIdx.x * 64;
  __shared__ __align__(16) unsigned short Ts[64 * 192];   // 24 KB swizzled [p][c]
  const int tid = threadIdx.x;
  const int wv = tid >> 6;                         // 0..5, wave owns rows 32*wv..+31
  const int lane = tid & 63;
  const int ln = lane & 15, mq = lane >> 4;
  const float* Mb = Mw + (size_t)b * CC2;

  // staging map: c-quad c0 = (tid>>3)*4 (48 quads), px-quad pq = tid&7 (8 per section)
  const int c0 = (tid >> 3) * 4;
  const int pq = tid & 7;
  const float* xsrc = xin + ((size_t)b * C_ + c0) * N_ + p0 + pq * 4;

  float4 ldA[4], ldB[4];
#pragma unroll
  for (int l = 0; l < 4; ++l) ldA[l] = *(const float4*)(xsrc + (size_t)l * N_);

  // M fragments (bf16) + bias, loaded once per block
  u16x8 afr[6][2];
  float bo[2][4];
#pragma unroll
  for (int i = 0; i < 2; ++i) {
    int row = 32 * wv + 16 * i + ln;
#pragma unroll
    for (int kc = 0; kc < 6; ++kc) {
      const float* src = Mb + row * C_ + kc * 32 + mq * 8;
      float4 u0 = *(const float4*)(src);
      float4 u1 = *(const float4*)(src + 4);
      uint32x4 w;
      w[0] = pkbf(u0.x, u0.y); w[1] = pkbf(u0.z, u0.w);
      w[2] = pkbf(u1.x, u1.y); w[3] = pkbf(u1.z, u1.w);
      afr[kc][i] = __builtin_bit_cast(u16x8, w);
    }
#pragma unroll
    for (int r = 0; r < 4; ++r) bo[i][r] = bias2[32 * wv + 16 * i + mq * 4 + r];
  }

  auto stage_write = [&](const float4* ld, int sbase) {
#pragma unroll
    for (int e = 0; e < 4; ++e) {                  // e compile-time: direct .x/.y/.z/.w
      int p = sbase + pq * 4 + e;
      int idx = p * 192 + ((((c0 >> 3) ^ ((p >> 1) & 7)) << 3) | (c0 & 7));
      uint2 pk;
      pk.x = pkbf(f4get(ld[0], e), f4get(ld[1], e));
      pk.y = pkbf(f4get(ld[2], e), f4get(ld[3], e));
      *(uint2*)&Ts[idx] = pk;                      // ds_write_b64
    }
  };

  auto compute = [&](int pt) {
    const int p = pt * 16 + ln;
    const int pkey = (p >> 1) & 7;
    f32x4 acc0 = (f32x4)0.0f, acc1 = (f32x4)0.0f;
#pragma unroll
    for (int kc = 0; kc < 6; ++kc) {
      u16x8 bf = *(const u16x8*)&Ts[p * 192 + (((kc * 4 + mq) ^ pkey) << 3)];
      acc0 = mfma16(afr[kc][0], bf, acc0);
      acc1 = mfma16(afr[kc][1], bf, acc1);
    }
    const int pp = p0 + p;
#pragma unroll
    for (int r = 0; r < 4; ++r) {
      int row0 = 32 * wv + mq * 4 + r;
      out[((size_t)b * C_ + row0) * N_ + pp] = acc0[r] + bo[0][r];
      out[((size_t)b * C_ + row0 + 16) * N_ + pp] = acc1[r] + bo[1][r];
    }
  };

  stage_write(ldA, 0);
  __syncthreads();
#pragma unroll
  for (int l = 0; l < 4; ++l) ldB[l] = *(const float4*)(xsrc + 32 + (size_t)l * N_);
  compute(0);
  compute(1);
  stage_write(ldB, 32);                            // waits vmcnt here, after MFMA
  __syncthreads();
  compute(2);
  compute(3);
}

extern "C" void kernel_launch(void* const* d_in, const int* in_sizes, int n_in,
                              void* d_out, int out_size, void* d_ws, size_t ws_size,
                              hipStream_t stream) {
  const float* xin    = (const float*)d_in[0];
  const float* wsplit = (const float*)d_in[1];
  const float* wq     = (const float*)d_in[2];
  const float* wk     = (const float*)d_in[3];
  const float* wv     = (const float*)d_in[4];
  const float* wproj  = (const float*)d_in[5];
  const float* bproj  = (const float*)d_in[6];
  const float* wout   = (const float*)d_in[7];
  float* out = (float*)d_out;

  float* ws = (float*)d_ws;
  float* G     = ws;                         // B*CC2
  float* Wq    = G + (size_t)B_ * CC2;       // CC2
  float* WqT   = Wq + CC2;
  float* Wk    = WqT + CC2;
  float* Wv    = Wk + CC2;
  float* Wo2   = Wv + CC2;
  float* bias2 = Wo2 + CC2;                  // 256
  float* Tk    = bias2 + 256;                // B*CC2
  float* Tv    = Tk + (size_t)B_ * CC2;
  float* Mw    = Tv + (size_t)B_ * CC2;
  float* qn    = Mw + (size_t)B_ * CC2;      // B*C_ (pad 256)
  float* P     = qn + 256 * B_;              // B*NCHUNK*CC2 (37.7 MB) if it fits

  size_t base_floats = (size_t)(P - ws);
  size_t need_bytes = (base_floats + (size_t)B_ * NCHUNK * CC2) * sizeof(float);
  bool use_partials = ws_size >= need_bytes;

  fold_kernel<<<(4 * CC2 + 255) / 256, 256, 0, stream>>>(
      wsplit, wq, wk, wv, wproj, bproj, wout, Wq, WqT, Wk, Wv, Wo2, bias2);

  if (use_partials) {
    gram3_kernel<false><<<dim3(NCHUNK, 2, B_), 384, 0, stream>>>(xin, P);
    const float* Pc = P;
    void* args[] = {(void*)&Pc, (void*)&G, (void*)&Wk, (void*)&Wq, (void*)&WqT,
                    (void*)&Wv, (void*)&Wo2, (void*)&Tk, (void*)&qn, (void*)&Tv,
                    (void*)&Mw};
    hipLaunchCooperativeKernel((const void*)middle_kernel<true>, dim3(512), dim3(256),
                               args, 0, stream);
  } else {
    hipMemsetAsync(G, 0, (size_t)B_ * CC2 * sizeof(float), stream);
    gram3_kernel<true><<<dim3(NCHUNK, 2, B_), 384, 0, stream>>>(xin, G);
    const float* Pc = G;                     // unused in SUMP=false
    void* args[] = {(void*)&Pc, (void*)&G, (void*)&Wk, (void*)&Wq, (void*)&WqT,
                    (void*)&Wv, (void*)&Wo2, (void*)&Tk, (void*)&qn, (void*)&Tv,
                    (void*)&Mw};
    hipLaunchCooperativeKernel((const void*)middle_kernel<false>, dim3(512), dim3(256),
                               args, 0, stream);
  }

  final3_kernel<<<dim3(N_ / 64, B_), 384, 0, stream>>>(xin, Mw, bias2, out);
}

// Round 5
// 366.732 us; speedup vs baseline: 1.7749x; 1.7749x over previous
//
#include <hip/hip_runtime.h>

// out[b] = M[b] @ X[b] + bias2, where (X = x_in[b] as [192,16384])
//   G[b]  = X X^T (Gram) ; Wq'=w_q@w_split etc.; Wo2=w_out@w_proj; bias2=w_out@b_proj
//   U = [Wk';Wq'] G ; Tk = U[0:192] ; kn[d]=sqrt(U_k[d]·Wk'[d]) ; qn[d]=sqrt(U_q[d]·Wq'[d])
//   S = Tk Wq'^T ; A = softmax_rows(S/(kn⊗qn)) ; Tv = A Wv' ; M = Wo2 Tv
// All GEMM-shaped phases use bf16 MFMA 16x16x32 with fp32 accum. The middle
// (tkqn2/attn2/m2) is 3 tiny MFMA kernels replacing 4 scalar-loop kernels that
// cost ~160 us for ~5 us of matrix work (round-4 post-mortem).

static constexpr int B_ = 8;
static constexpr int C_ = 192;
static constexpr int N_ = 16384;
static constexpr int CC2 = C_ * C_;
static constexpr int NCHUNK = 32;

using u16x8 = __attribute__((ext_vector_type(8))) unsigned short;
using bf16x8 = __attribute__((ext_vector_type(8))) __bf16;
using f32x4 = __attribute__((ext_vector_type(4))) float;
using uint32x4 = __attribute__((ext_vector_type(4))) unsigned int;

__device__ __forceinline__ unsigned short f2bf(float f) {
  unsigned int u = __builtin_bit_cast(unsigned int, f);
  u += 0x7FFFu + ((u >> 16) & 1u);   // RNE
  return (unsigned short)(u >> 16);
}

// packed f32x2 -> bf16x2 (compiler emits v_cvt_pk_bf16_f32; RNE)
__device__ __forceinline__ unsigned int pkbf(float lo, float hi) {
  unsigned short a = __builtin_bit_cast(unsigned short, (__bf16)lo);
  unsigned short b = __builtin_bit_cast(unsigned short, (__bf16)hi);
  return (unsigned int)a | ((unsigned int)b << 16);
}

// 8 consecutive fp32 (16B-aligned) -> bf16 fragment
__device__ __forceinline__ u16x8 ld8bf(const float* p) {
  float4 u0 = *(const float4*)p;
  float4 u1 = *(const float4*)(p + 4);
  uint32x4 w;
  w[0] = pkbf(u0.x, u0.y); w[1] = pkbf(u0.z, u0.w);
  w[2] = pkbf(u1.x, u1.y); w[3] = pkbf(u1.z, u1.w);
  return __builtin_bit_cast(u16x8, w);
}

__device__ __forceinline__ float f4get(const float4& v, int e) {
  return (e == 0) ? v.x : (e == 1) ? v.y : (e == 2) ? v.z : v.w;
}

__device__ __forceinline__ f32x4 mfma16(u16x8 a, u16x8 b, f32x4 c) {
  return __builtin_amdgcn_mfma_f32_16x16x32_bf16(
      __builtin_bit_cast(bf16x8, a), __builtin_bit_cast(bf16x8, b), c, 0, 0, 0);
}

// ---------------- fold weights ----------------
__global__ void fold_kernel(const float* __restrict__ wsplit, const float* __restrict__ wq,
                            const float* __restrict__ wk, const float* __restrict__ wv,
                            const float* __restrict__ wproj, const float* __restrict__ bproj,
                            const float* __restrict__ wout,
                            float* __restrict__ Wq, float* __restrict__ WvT,
                            float* __restrict__ Wk, float* __restrict__ Wv,
                            float* __restrict__ Wo2, float* __restrict__ bias2) {
  int idx = blockIdx.x * 256 + threadIdx.x;
  if (idx < C_) {
    float s = 0.f;
    for (int c = 0; c < C_; ++c) s += wout[idx * C_ + c] * bproj[c];
    bias2[idx] = s;
  }
  if (idx >= 4 * CC2) return;
  int which = idx / CC2;
  int rem = idx % CC2;
  int o = rem / C_, c = rem % C_;
  const float* A = (which == 0) ? wq : (which == 1) ? wk : (which == 2) ? wv : wout;
  const float* Bm = (which == 3) ? wproj : wsplit;
  float s = 0.f;
  for (int e = 0; e < C_; ++e) s += A[o * C_ + e] * Bm[e * C_ + c];
  if (which == 0) Wq[rem] = s;
  else if (which == 1) Wk[rem] = s;
  else if (which == 2) { Wv[rem] = s; WvT[c * C_ + o] = s; }
  else Wo2[rem] = s;
}

// ---------------- Gram: row-split x2, double-buffered pipeline (round-2 measured) ----
template <bool ATOMIC>
__global__ __launch_bounds__(384) void gram3_kernel(const float* __restrict__ xin,
                                                    float* __restrict__ dst) {
  const int b = blockIdx.z, half = blockIdx.y, ch = blockIdx.x;
  const int k0 = ch * 512;
  __shared__ unsigned short Xs[2][C_][72];         // dbuf, pitch 72 (2-way = free)
  const int tid = threadIdx.x;
  const int wv = tid >> 6;                         // 0..5
  const int lane = tid & 63;
  const int ln = lane & 15, mq = lane >> 4;
  const int arow0 = half * 96 + wv * 16;           // this wave's 16 G-rows
  const int cbase = tid >> 4;                      // 0..23
  const int k4 = tid & 15;
  const float* xb = xin + (size_t)b * C_ * N_;

  f32x4 acc[12];
#pragma unroll
  for (int j = 0; j < 12; ++j) acc[j] = (f32x4)0.0f;

  float4 ld[8];
  auto load_stage = [&](int kbase) {
#pragma unroll
    for (int j = 0; j < 8; ++j)
      ld[j] = *(const float4*)(xb + (size_t)(j * 24 + cbase) * N_ + kbase + k4 * 4);
  };
  auto write_stage = [&](int buf) {
#pragma unroll
    for (int j = 0; j < 8; ++j) {
      uint2 pk;
      pk.x = pkbf(ld[j].x, ld[j].y);
      pk.y = pkbf(ld[j].z, ld[j].w);
      *(uint2*)&Xs[buf][j * 24 + cbase][k4 * 4] = pk;    // ds_write_b64
    }
  };

  load_stage(k0);
  write_stage(0);
  __syncthreads();
  for (int s = 0; s < 8; ++s) {                    // 8 stages of 64 k
    if (s < 7) load_stage(k0 + (s + 1) * 64);      // prefetch overlaps MFMA
    const int cb = s & 1;
#pragma unroll
    for (int ks = 0; ks < 2; ++ks) {
      const int kk = ks * 32 + mq * 8;
      u16x8 a0 = *(const u16x8*)&Xs[cb][arow0 + ln][kk];
#pragma unroll
      for (int ct = 0; ct < 12; ++ct) {
        u16x8 bf = *(const u16x8*)&Xs[cb][ct * 16 + ln][kk];
        acc[ct] = mfma16(a0, bf, acc[ct]);
      }
    }
    if (s < 7) {
      write_stage(cb ^ 1);   // safe: cb^1 last read a full barrier ago
      __syncthreads();
    }
  }
  float* out = ATOMIC ? dst + (size_t)b * CC2
                      : dst + ((size_t)b * NCHUNK + ch) * CC2;
#pragma unroll
  for (int ct = 0; ct < 12; ++ct)
#pragma unroll
    for (int r = 0; r < 4; ++r) {
      int row = arow0 + mq * 4 + r;
      int col = ct * 16 + ln;
      if (ATOMIC) atomicAdd(&out[row * C_ + col], acc[ct][r]);
      else out[row * C_ + col] = acc[ct][r];
    }
}

// reduce 32 partials -> G. float4. grid (CC2/1024, 8), 256 thr.
__global__ void gsum_kernel(const float* __restrict__ P, float* __restrict__ G) {
  const int j = (blockIdx.x * 256 + threadIdx.x) * 4;
  const int b = blockIdx.y;
  const float* base = P + (size_t)b * NCHUNK * CC2 + j;
  float4 s = {0.f, 0.f, 0.f, 0.f};
#pragma unroll
  for (int ch = 0; ch < NCHUNK; ++ch) {
    float4 v = *(const float4*)(base + (size_t)ch * CC2);
    s.x += v.x; s.y += v.y; s.z += v.z; s.w += v.w;
  }
  *(float4*)(G + (size_t)b * CC2 + j) = s;
}

// ---------------- middle v2: 3 tiny MFMA kernels ----------------
// K1: U = [Wk;Wq]·G (384x192, G symmetric so B-frags = G rows). Epilogue: row-dots
// give kn (rows<192) and qn (rows>=192). Writes Tk = U[0:192] fp32.
// grid (6, B_) = 48 blocks, 256 thr (4 waves x 16 rows).
__global__ __launch_bounds__(256) void tkqn2_kernel(
    const float* __restrict__ Wk, const float* __restrict__ Wq,
    const float* __restrict__ G, float* __restrict__ Tk,
    float* __restrict__ kn, float* __restrict__ qn) {
  const int b = blockIdx.y;
  const int row0 = blockIdx.x * 64;                // of 384 virtual rows [Wk;Wq]
  const int tid = threadIdx.x;
  const int w = tid >> 6, lane = tid & 63;
  const int ln = lane & 15, mq = lane >> 4;
  const int rbase = row0 + w * 16;
  const bool isq = rbase >= C_;
  const float* W2 = isq ? Wq : Wk;
  const int rloc = isq ? rbase - C_ : rbase;
  const float* Gb = G + (size_t)b * CC2;

  f32x4 acc[12];
#pragma unroll
  for (int j = 0; j < 12; ++j) acc[j] = (f32x4)0.0f;

  for (int kc = 0; kc < 6; ++kc) {
    u16x8 a = ld8bf(W2 + (size_t)(rloc + ln) * C_ + kc * 32 + mq * 8);
#pragma unroll
    for (int ct = 0; ct < 12; ++ct) {
      u16x8 g = ld8bf(Gb + (size_t)(ct * 16 + ln) * C_ + kc * 32 + mq * 8);
      acc[ct] = mfma16(a, g, acc[ct]);
    }
  }
  // row-dots: nrm[row] = U[row]·W2[row]
  const float* wr = W2 + (size_t)(rloc + mq * 4) * C_;
  float nrm[4] = {0.f, 0.f, 0.f, 0.f};
#pragma unroll
  for (int ct = 0; ct < 12; ++ct)
#pragma unroll
    for (int r = 0; r < 4; ++r)
      nrm[r] += acc[ct][r] * wr[r * C_ + ct * 16 + ln];
#pragma unroll
  for (int m = 1; m < 16; m <<= 1)
#pragma unroll
    for (int r = 0; r < 4; ++r) nrm[r] += __shfl_xor(nrm[r], m);
  if (ln == 0) {
#pragma unroll
    for (int r = 0; r < 4; ++r) {
      float v = fmaxf(sqrtf(fmaxf(nrm[r], 0.f)), 1e-12f);
      int row = rbase + mq * 4 + r;
      if (row < C_) kn[b * 256 + row] = v;
      else qn[b * 256 + row - C_] = v;
    }
  }
  if (!isq) {
#pragma unroll
    for (int ct = 0; ct < 12; ++ct)
#pragma unroll
      for (int r = 0; r < 4; ++r)
        Tk[((size_t)b * C_ + rbase + mq * 4 + r) * C_ + ct * 16 + ln] = acc[ct][r];
  }
}

// K2: S = Tk·Wq^T -> scale 1/(kn qn) -> row softmax -> A (LDS, bf16) -> Tv = A·Wv'
// (via WvT rows) -> write Tv TRANSPOSED as packed bf16 (the layout m2 needs).
// grid (3, B_) = 24 blocks, 256 thr (4 waves x 16 rows).
__global__ __launch_bounds__(256) void attn2_kernel(
    const float* __restrict__ Tk, const float* __restrict__ Wq,
    const float* __restrict__ WvT, const float* __restrict__ kn,
    const float* __restrict__ qn, unsigned short* __restrict__ Tvt) {
  __shared__ unsigned short As[64 * 200];          // pad 200: rows spread banks
  const int b = blockIdx.y;
  const int row0 = blockIdx.x * 64;
  const int tid = threadIdx.x;
  const int w = tid >> 6, lane = tid & 63;
  const int ln = lane & 15, mq = lane >> 4;
  const int rbase = row0 + w * 16;

  f32x4 acc[12];
#pragma unroll
  for (int j = 0; j < 12; ++j) acc[j] = (f32x4)0.0f;
  for (int kc = 0; kc < 6; ++kc) {
    u16x8 a = ld8bf(Tk + ((size_t)b * C_ + rbase + ln) * C_ + kc * 32 + mq * 8);
#pragma unroll
    for (int ct = 0; ct < 12; ++ct) {
      u16x8 q = ld8bf(Wq + (size_t)(ct * 16 + ln) * C_ + kc * 32 + mq * 8);
      acc[ct] = mfma16(a, q, acc[ct]);
    }
  }
  float rkn[4], rqn[12];
#pragma unroll
  for (int r = 0; r < 4; ++r) rkn[r] = kn[b * 256 + rbase + mq * 4 + r];
#pragma unroll
  for (int ct = 0; ct < 12; ++ct) rqn[ct] = qn[b * 256 + ct * 16 + ln];

  float mx[4] = {-1e30f, -1e30f, -1e30f, -1e30f};
#pragma unroll
  for (int ct = 0; ct < 12; ++ct)
#pragma unroll
    for (int r = 0; r < 4; ++r) {
      float l = acc[ct][r] / (rkn[r] * rqn[ct]);
      acc[ct][r] = l;
      mx[r] = fmaxf(mx[r], l);
    }
#pragma unroll
  for (int m = 1; m < 16; m <<= 1)
#pragma unroll
    for (int r = 0; r < 4; ++r) mx[r] = fmaxf(mx[r], __shfl_xor(mx[r], m));
  float sm[4] = {0.f, 0.f, 0.f, 0.f};
#pragma unroll
  for (int ct = 0; ct < 12; ++ct)
#pragma unroll
    for (int r = 0; r < 4; ++r) {
      float e = expf(acc[ct][r] - mx[r]);
      acc[ct][r] = e;
      sm[r] += e;
    }
#pragma unroll
  for (int m = 1; m < 16; m <<= 1)
#pragma unroll
    for (int r = 0; r < 4; ++r) sm[r] += __shfl_xor(sm[r], m);
  float inv[4];
#pragma unroll
  for (int r = 0; r < 4; ++r) inv[r] = 1.f / sm[r];
#pragma unroll
  for (int ct = 0; ct < 12; ++ct)
#pragma unroll
    for (int r = 0; r < 4; ++r) {
      int lrow = w * 16 + mq * 4 + r;
      As[lrow * 200 + ct * 16 + ln] = f2bf(acc[ct][r] * inv[r]);
    }
  __syncthreads();

  f32x4 tv[12];
#pragma unroll
  for (int j = 0; j < 12; ++j) tv[j] = (f32x4)0.0f;
  for (int kc = 0; kc < 6; ++kc) {
    u16x8 a2 = *(const u16x8*)&As[(w * 16 + ln) * 200 + kc * 32 + mq * 8];
#pragma unroll
    for (int ct = 0; ct < 12; ++ct) {
      u16x8 q = ld8bf(WvT + (size_t)(ct * 16 + ln) * C_ + kc * 32 + mq * 8);
      tv[ct] = mfma16(a2, q, tv[ct]);
    }
  }
#pragma unroll
  for (int ct = 0; ct < 12; ++ct) {
    uint2 pk;
    pk.x = pkbf(tv[ct][0], tv[ct][1]);
    pk.y = pkbf(tv[ct][2], tv[ct][3]);
    *(uint2*)&Tvt[((size_t)b * C_ + ct * 16 + ln) * C_ + row0 + w * 16 + mq * 4] = pk;
  }
}

// K3: M = Wo2 · Tv. P = Wo2 rows (fp32->bf16), Q = Tvt rows (bf16 direct 16B loads).
// grid (3, B_) = 24 blocks, 256 thr.
__global__ __launch_bounds__(256) void m2_kernel(
    const float* __restrict__ Wo2, const unsigned short* __restrict__ Tvt,
    float* __restrict__ Mw) {
  const int b = blockIdx.y;
  const int row0 = blockIdx.x * 64;
  const int tid = threadIdx.x;
  const int w = tid >> 6, lane = tid & 63;
  const int ln = lane & 15, mq = lane >> 4;
  const int rbase = row0 + w * 16;

  f32x4 acc[12];
#pragma unroll
  for (int j = 0; j < 12; ++j) acc[j] = (f32x4)0.0f;
  for (int kc = 0; kc < 6; ++kc) {
    u16x8 a = ld8bf(Wo2 + (size_t)(rbase + ln) * C_ + kc * 32 + mq * 8);
#pragma unroll
    for (int ct = 0; ct < 12; ++ct) {
      u16x8 q = *(const u16x8*)&Tvt[((size_t)b * C_ + ct * 16 + ln) * C_ + kc * 32 + mq * 8];
      acc[ct] = mfma16(a, q, acc[ct]);
    }
  }
#pragma unroll
  for (int ct = 0; ct < 12; ++ct)
#pragma unroll
    for (int r = 0; r < 4; ++r)
      Mw[(size_t)b * CC2 + (rbase + mq * 4 + r) * C_ + ct * 16 + ln] = acc[ct][r];
}

// ---------------- final: out[b] = M[b] @ X[b] + bias2, bf16 MFMA ----------------
// v3b (measured 59.4 us): 64-px blocks, 24 KB LDS, 2-section register-prefetch,
// packed b64 LDS writes, swizzle key (p>>1)&7, __launch_bounds__(384,4) (no spill).
__global__ __launch_bounds__(384, 4) void final3_kernel(const float* __restrict__ xin,
                                                        const float* __restrict__ Mw,
                                                        const float* __restrict__ bias2,
                                                        float* __restrict__ out) {
  const int b = blockIdx.y;
  const int p0 = blockIdx.x * 64;
  __shared__ __align__(16) unsigned short Ts[64 * 192];   // 24 KB swizzled [p][c]
  const int tid = threadIdx.x;
  const int wv = tid >> 6;                         // 0..5, wave owns rows 32*wv..+31
  const int lane = tid & 63;
  const int ln = lane & 15, mq = lane >> 4;
  const float* Mb = Mw + (size_t)b * CC2;

  // staging map: c-quad c0 = (tid>>3)*4 (48 quads), px-quad pq = tid&7 (8 per section)
  const int c0 = (tid >> 3) * 4;
  const int pq = tid & 7;
  const float* xsrc = xin + ((size_t)b * C_ + c0) * N_ + p0 + pq * 4;

  float4 ldA[4], ldB[4];
#pragma unroll
  for (int l = 0; l < 4; ++l) ldA[l] = *(const float4*)(xsrc + (size_t)l * N_);

  // M fragments (bf16) + bias, loaded once per block
  u16x8 afr[6][2];
  float bo[2][4];
#pragma unroll
  for (int i = 0; i < 2; ++i) {
    int row = 32 * wv + 16 * i + ln;
#pragma unroll
    for (int kc = 0; kc < 6; ++kc) {
      const float* src = Mb + row * C_ + kc * 32 + mq * 8;
      float4 u0 = *(const float4*)(src);
      float4 u1 = *(const float4*)(src + 4);
      uint32x4 w;
      w[0] = pkbf(u0.x, u0.y); w[1] = pkbf(u0.z, u0.w);
      w[2] = pkbf(u1.x, u1.y); w[3] = pkbf(u1.z, u1.w);
      afr[kc][i] = __builtin_bit_cast(u16x8, w);
    }
#pragma unroll
    for (int r = 0; r < 4; ++r) bo[i][r] = bias2[32 * wv + 16 * i + mq * 4 + r];
  }

  auto stage_write = [&](const float4* ld, int sbase) {
#pragma unroll
    for (int e = 0; e < 4; ++e) {                  // e compile-time: direct .x/.y/.z/.w
      int p = sbase + pq * 4 + e;
      int idx = p * 192 + ((((c0 >> 3) ^ ((p >> 1) & 7)) << 3) | (c0 & 7));
      uint2 pk;
      pk.x = pkbf(f4get(ld[0], e), f4get(ld[1], e));
      pk.y = pkbf(f4get(ld[2], e), f4get(ld[3], e));
      *(uint2*)&Ts[idx] = pk;                      // ds_write_b64
    }
  };

  auto compute = [&](int pt) {
    const int p = pt * 16 + ln;
    const int pkey = (p >> 1) & 7;
    f32x4 acc0 = (f32x4)0.0f, acc1 = (f32x4)0.0f;
#pragma unroll
    for (int kc = 0; kc < 6; ++kc) {
      u16x8 bf = *(const u16x8*)&Ts[p * 192 + (((kc * 4 + mq) ^ pkey) << 3)];
      acc0 = mfma16(afr[kc][0], bf, acc0);
      acc1 = mfma16(afr[kc][1], bf, acc1);
    }
    const int pp = p0 + p;
#pragma unroll
    for (int r = 0; r < 4; ++r) {
      int row0 = 32 * wv + mq * 4 + r;
      out[((size_t)b * C_ + row0) * N_ + pp] = acc0[r] + bo[0][r];
      out[((size_t)b * C_ + row0 + 16) * N_ + pp] = acc1[r] + bo[1][r];
    }
  };

  stage_write(ldA, 0);
  __syncthreads();
#pragma unroll
  for (int l = 0; l < 4; ++l) ldB[l] = *(const float4*)(xsrc + 32 + (size_t)l * N_);
  compute(0);
  compute(1);
  stage_write(ldB, 32);                            // waits vmcnt here, after MFMA
  __syncthreads();
  compute(2);
  compute(3);
}

extern "C" void kernel_launch(void* const* d_in, const int* in_sizes, int n_in,
                              void* d_out, int out_size, void* d_ws, size_t ws_size,
                              hipStream_t stream) {
  const float* xin    = (const float*)d_in[0];
  const float* wsplit = (const float*)d_in[1];
  const float* wq     = (const float*)d_in[2];
  const float* wk     = (const float*)d_in[3];
  const float* wv     = (const float*)d_in[4];
  const float* wproj  = (const float*)d_in[5];
  const float* bproj  = (const float*)d_in[6];
  const float* wout   = (const float*)d_in[7];
  float* out = (float*)d_out;

  float* ws = (float*)d_ws;
  float* G     = ws;                         // B*CC2
  float* Wq    = G + (size_t)B_ * CC2;       // CC2
  float* WvT   = Wq + CC2;
  float* Wk    = WvT + CC2;
  float* Wv    = Wk + CC2;
  float* Wo2   = Wv + CC2;
  float* bias2 = Wo2 + CC2;                  // 256
  float* Tk    = bias2 + 256;                // B*CC2
  float* Tvt_f = Tk + (size_t)B_ * CC2;      // B*CC2 (bf16 packed, half used)
  float* Mw    = Tvt_f + (size_t)B_ * CC2;
  float* qn    = Mw + (size_t)B_ * CC2;      // 256*B
  float* kn    = qn + 256 * B_;              // 256*B
  float* P     = kn + 256 * B_;              // B*NCHUNK*CC2 (37.7 MB) if it fits

  size_t base_floats = (size_t)(P - ws);
  size_t need_bytes = (base_floats + (size_t)B_ * NCHUNK * CC2) * sizeof(float);
  bool use_partials = ws_size >= need_bytes;

  fold_kernel<<<(4 * CC2 + 255) / 256, 256, 0, stream>>>(
      wsplit, wq, wk, wv, wproj, bproj, wout, Wq, WvT, Wk, Wv, Wo2, bias2);
  if (use_partials) {
    gram3_kernel<false><<<dim3(NCHUNK, 2, B_), 384, 0, stream>>>(xin, P);
    gsum_kernel<<<dim3(CC2 / 1024, B_), 256, 0, stream>>>(P, G);
  } else {
    hipMemsetAsync(G, 0, (size_t)B_ * CC2 * sizeof(float), stream);
    gram3_kernel<true><<<dim3(NCHUNK, 2, B_), 384, 0, stream>>>(xin, G);
  }
  tkqn2_kernel<<<dim3(6, B_), 256, 0, stream>>>(Wk, Wq, G, Tk, kn, qn);
  attn2_kernel<<<dim3(3, B_), 256, 0, stream>>>(Tk, Wq, WvT, kn, qn,
                                                (unsigned short*)Tvt_f);
  m2_kernel<<<dim3(3, B_), 256, 0, stream>>>(Wo2, (const unsigned short*)Tvt_f, Mw);
  final3_kernel<<<dim3(N_ / 64, B_), 384, 0, stream>>>(xin, Mw, bias2, out);
}

// Round 6
// 312.331 us; speedup vs baseline: 2.0841x; 1.1742x over previous
//
#include <hip/hip_runtime.h>

// out[b] = M[b] @ X[b] + bias2, where (X = x_in[b] as [192,16384])
//   G[b]  = X X^T (Gram) ; Wq'=w_q@w_split etc.; Wo2=w_out@w_proj; bias2=w_out@b_proj
//   U = [Wk';Wq'] G ; Tk = U[0:192] ; kn[d]=sqrt(U_k[d]·Wk'[d]) ; qn[d]=sqrt(U_q[d]·Wq'[d])
//   S = Tk Wq'^T ; A = softmax_rows(S/(kn⊗qn)) ; Tv = A Wv' ; M = Wo2 Tv
// All GEMM phases use bf16 MFMA 16x16x32, fp32 accum. Round-5 post-mortem: the
// middle MFMA kernels were latency-bound (60 us each, 1% occupancy, ~900 cy per
// serialized fragment load; compiler gave 80 VGPR and couldn't hoist loads).
// v2 middle: B-matrices staged to LDS in one parallel coalesced pass (pitch 200
// u16 = conflict-free for both writes and ds_read_b128), A-frags issued before
// staging so their latency hides under it, launch_bounds opened up.

static constexpr int B_ = 8;
static constexpr int C_ = 192;
static constexpr int N_ = 16384;
static constexpr int CC2 = C_ * C_;
static constexpr int NCHUNK = 32;

using u16x8 = __attribute__((ext_vector_type(8))) unsigned short;
using bf16x8 = __attribute__((ext_vector_type(8))) __bf16;
using f32x4 = __attribute__((ext_vector_type(4))) float;
using uint32x4 = __attribute__((ext_vector_type(4))) unsigned int;

__device__ __forceinline__ unsigned short f2bf(float f) {
  unsigned int u = __builtin_bit_cast(unsigned int, f);
  u += 0x7FFFu + ((u >> 16) & 1u);   // RNE
  return (unsigned short)(u >> 16);
}

// packed f32x2 -> bf16x2 (compiler emits v_cvt_pk_bf16_f32; RNE)
__device__ __forceinline__ unsigned int pkbf(float lo, float hi) {
  unsigned short a = __builtin_bit_cast(unsigned short, (__bf16)lo);
  unsigned short b = __builtin_bit_cast(unsigned short, (__bf16)hi);
  return (unsigned int)a | ((unsigned int)b << 16);
}

// 8 consecutive fp32 (16B-aligned) -> bf16 fragment
__device__ __forceinline__ u16x8 ld8bf(const float* p) {
  float4 u0 = *(const float4*)p;
  float4 u1 = *(const float4*)(p + 4);
  uint32x4 w;
  w[0] = pkbf(u0.x, u0.y); w[1] = pkbf(u0.z, u0.w);
  w[2] = pkbf(u1.x, u1.y); w[3] = pkbf(u1.z, u1.w);
  return __builtin_bit_cast(u16x8, w);
}

__device__ __forceinline__ float f4get(const float4& v, int e) {
  return (e == 0) ? v.x : (e == 1) ? v.y : (e == 2) ? v.z : v.w;
}

__device__ __forceinline__ f32x4 mfma16(u16x8 a, u16x8 b, f32x4 c) {
  return __builtin_amdgcn_mfma_f32_16x16x32_bf16(
      __builtin_bit_cast(bf16x8, a), __builtin_bit_cast(bf16x8, b), c, 0, 0, 0);
}

// stage fp32 [192][192] row-major -> LDS bf16, row pitch 200 u16 (400 B).
// 9216 float4 chunks over 256 threads = 36 each, all independent (pipelines).
// pitch 200: rows shift 4 banks/row -> staging writes and b128 frag reads both
// spread evenly over 32 banks (pitch 192 would alias 8x).
__device__ __forceinline__ void stage_f32_bf16(const float* __restrict__ src,
                                               unsigned short* __restrict__ lds,
                                               int tid) {
#pragma unroll
  for (int i = 0; i < 36; ++i) {
    int idx = i * 256 + tid;
    int row = idx / 48, c4 = idx % 48;
    float4 v = *(const float4*)(src + (size_t)row * C_ + c4 * 4);
    uint2 pk; pk.x = pkbf(v.x, v.y); pk.y = pkbf(v.z, v.w);
    *(uint2*)&lds[row * 200 + c4 * 4] = pk;        // ds_write_b64
  }
}

// stage bf16 [192][192] -> LDS pitch 200 u16. 4608 16B chunks / 256 thr = 18 each.
__device__ __forceinline__ void stage_bf16(const unsigned short* __restrict__ src,
                                           unsigned short* __restrict__ lds, int tid) {
#pragma unroll
  for (int i = 0; i < 18; ++i) {
    int idx = i * 256 + tid;
    int row = idx / 24, c8 = idx % 24;
    uint4 v = *(const uint4*)(src + (size_t)row * C_ + c8 * 8);
    *(uint4*)&lds[row * 200 + c8 * 8] = v;         // ds_write_b128
  }
}

// ---------------- fold weights ----------------
__global__ void fold_kernel(const float* __restrict__ wsplit, const float* __restrict__ wq,
                            const float* __restrict__ wk, const float* __restrict__ wv,
                            const float* __restrict__ wproj, const float* __restrict__ bproj,
                            const float* __restrict__ wout,
                            float* __restrict__ Wq, float* __restrict__ WvT,
                            float* __restrict__ Wk, float* __restrict__ Wv,
                            float* __restrict__ Wo2, float* __restrict__ bias2) {
  int idx = blockIdx.x * 256 + threadIdx.x;
  if (idx < C_) {
    float s = 0.f;
    for (int c = 0; c < C_; ++c) s += wout[idx * C_ + c] * bproj[c];
    bias2[idx] = s;
  }
  if (idx >= 4 * CC2) return;
  int which = idx / CC2;
  int rem = idx % CC2;
  int o = rem / C_, c = rem % C_;
  const float* A = (which == 0) ? wq : (which == 1) ? wk : (which == 2) ? wv : wout;
  const float* Bm = (which == 3) ? wproj : wsplit;
  float s = 0.f;
  for (int e = 0; e < C_; ++e) s += A[o * C_ + e] * Bm[e * C_ + c];
  if (which == 0) Wq[rem] = s;
  else if (which == 1) Wk[rem] = s;
  else if (which == 2) { Wv[rem] = s; WvT[c * C_ + o] = s; }
  else Wo2[rem] = s;
}

// ---------------- Gram: row-split x2, double-buffered pipeline (round-2 measured) ----
template <bool ATOMIC>
__global__ __launch_bounds__(384) void gram3_kernel(const float* __restrict__ xin,
                                                    float* __restrict__ dst) {
  const int b = blockIdx.z, half = blockIdx.y, ch = blockIdx.x;
  const int k0 = ch * 512;
  __shared__ unsigned short Xs[2][C_][72];         // dbuf, pitch 72 (2-way = free)
  const int tid = threadIdx.x;
  const int wv = tid >> 6;                         // 0..5
  const int lane = tid & 63;
  const int ln = lane & 15, mq = lane >> 4;
  const int arow0 = half * 96 + wv * 16;           // this wave's 16 G-rows
  const int cbase = tid >> 4;                      // 0..23
  const int k4 = tid & 15;
  const float* xb = xin + (size_t)b * C_ * N_;

  f32x4 acc[12];
#pragma unroll
  for (int j = 0; j < 12; ++j) acc[j] = (f32x4)0.0f;

  float4 ld[8];
  auto load_stage = [&](int kbase) {
#pragma unroll
    for (int j = 0; j < 8; ++j)
      ld[j] = *(const float4*)(xb + (size_t)(j * 24 + cbase) * N_ + kbase + k4 * 4);
  };
  auto write_stage = [&](int buf) {
#pragma unroll
    for (int j = 0; j < 8; ++j) {
      uint2 pk;
      pk.x = pkbf(ld[j].x, ld[j].y);
      pk.y = pkbf(ld[j].z, ld[j].w);
      *(uint2*)&Xs[buf][j * 24 + cbase][k4 * 4] = pk;    // ds_write_b64
    }
  };

  load_stage(k0);
  write_stage(0);
  __syncthreads();
  for (int s = 0; s < 8; ++s) {                    // 8 stages of 64 k
    if (s < 7) load_stage(k0 + (s + 1) * 64);      // prefetch overlaps MFMA
    const int cb = s & 1;
#pragma unroll
    for (int ks = 0; ks < 2; ++ks) {
      const int kk = ks * 32 + mq * 8;
      u16x8 a0 = *(const u16x8*)&Xs[cb][arow0 + ln][kk];
#pragma unroll
      for (int ct = 0; ct < 12; ++ct) {
        u16x8 bf = *(const u16x8*)&Xs[cb][ct * 16 + ln][kk];
        acc[ct] = mfma16(a0, bf, acc[ct]);
      }
    }
    if (s < 7) {
      write_stage(cb ^ 1);   // safe: cb^1 last read a full barrier ago
      __syncthreads();
    }
  }
  float* out = ATOMIC ? dst + (size_t)b * CC2
                      : dst + ((size_t)b * NCHUNK + ch) * CC2;
#pragma unroll
  for (int ct = 0; ct < 12; ++ct)
#pragma unroll
    for (int r = 0; r < 4; ++r) {
      int row = arow0 + mq * 4 + r;
      int col = ct * 16 + ln;
      if (ATOMIC) atomicAdd(&out[row * C_ + col], acc[ct][r]);
      else out[row * C_ + col] = acc[ct][r];
    }
}

// reduce 32 partials -> G. float4. grid (CC2/1024, 8), 256 thr.
__global__ void gsum_kernel(const float* __restrict__ P, float* __restrict__ G) {
  const int j = (blockIdx.x * 256 + threadIdx.x) * 4;
  const int b = blockIdx.y;
  const float* base = P + (size_t)b * NCHUNK * CC2 + j;
  float4 s = {0.f, 0.f, 0.f, 0.f};
#pragma unroll
  for (int ch = 0; ch < NCHUNK; ++ch) {
    float4 v = *(const float4*)(base + (size_t)ch * CC2);
    s.x += v.x; s.y += v.y; s.z += v.z; s.w += v.w;
  }
  *(float4*)(G + (size_t)b * CC2 + j) = s;
}

// ---------------- middle v3: LDS-staged small MFMA GEMMs ----------------
// K1: U = [Wk;Wq]·G. B = G[b] staged to LDS (76.8 KB, 2 blocks/CU). Epilogue
// row-dots give kn/qn. grid (6, B_) = 48 blocks, 256 thr.
__global__ __launch_bounds__(256, 2) void tkqn2_kernel(
    const float* __restrict__ Wk, const float* __restrict__ Wq,
    const float* __restrict__ G, float* __restrict__ Tk,
    float* __restrict__ kn, float* __restrict__ qn) {
  __shared__ __align__(16) unsigned short Gs[192 * 200];
  const int b = blockIdx.y;
  const int row0 = blockIdx.x * 64;                // of 384 virtual rows [Wk;Wq]
  const int tid = threadIdx.x;
  const int w = tid >> 6, lane = tid & 63;
  const int ln = lane & 15, mq = lane >> 4;
  const int rbase = row0 + w * 16;
  const bool isq = rbase >= C_;
  const float* W2 = isq ? Wq : Wk;
  const int rloc = isq ? rbase - C_ : rbase;
  const float* Gb = G + (size_t)b * CC2;

  // A-frags issue first; their latency hides under the staging pass
  u16x8 afr[6];
#pragma unroll
  for (int kc = 0; kc < 6; ++kc)
    afr[kc] = ld8bf(W2 + (size_t)(rloc + ln) * C_ + kc * 32 + mq * 8);

  stage_f32_bf16(Gb, Gs, tid);
  __syncthreads();

  f32x4 acc[12];
#pragma unroll
  for (int j = 0; j < 12; ++j) acc[j] = (f32x4)0.0f;
#pragma unroll
  for (int kc = 0; kc < 6; ++kc)
#pragma unroll
    for (int ct = 0; ct < 12; ++ct)
      acc[ct] = mfma16(afr[kc], *(const u16x8*)&Gs[(ct * 16 + ln) * 200 + kc * 32 + mq * 8],
                       acc[ct]);

  // row-dots: nrm[row] = U[row]·W2[row]
  const float* wr = W2 + (size_t)(rloc + mq * 4) * C_;
  float nrm[4] = {0.f, 0.f, 0.f, 0.f};
#pragma unroll
  for (int ct = 0; ct < 12; ++ct)
#pragma unroll
    for (int r = 0; r < 4; ++r)
      nrm[r] += acc[ct][r] * wr[r * C_ + ct * 16 + ln];
#pragma unroll
  for (int m = 1; m < 16; m <<= 1)
#pragma unroll
    for (int r = 0; r < 4; ++r) nrm[r] += __shfl_xor(nrm[r], m);
  if (ln == 0) {
#pragma unroll
    for (int r = 0; r < 4; ++r) {
      float v = fmaxf(sqrtf(fmaxf(nrm[r], 0.f)), 1e-12f);
      int row = rbase + mq * 4 + r;
      if (row < C_) kn[b * 256 + row] = v;
      else qn[b * 256 + row - C_] = v;
    }
  }
  if (!isq) {
#pragma unroll
    for (int ct = 0; ct < 12; ++ct)
#pragma unroll
      for (int r = 0; r < 4; ++r)
        Tk[((size_t)b * C_ + rbase + mq * 4 + r) * C_ + ct * 16 + ln] = acc[ct][r];
  }
}

// K2: S = Tk·Wq^T (Wq staged in Ws) -> softmax -> As -> Tv = A·Wv' (WvT re-staged
// into the same Ws) -> Tvt bf16. grid (3, B_) = 24 blocks, 256 thr, 102.4 KB LDS.
__global__ __launch_bounds__(256, 1) void attn2_kernel(
    const float* __restrict__ Tk, const float* __restrict__ Wq,
    const float* __restrict__ WvT, const float* __restrict__ kn,
    const float* __restrict__ qn, unsigned short* __restrict__ Tvt) {
  __shared__ __align__(16) unsigned short Ws[192 * 200];
  __shared__ __align__(16) unsigned short As[64 * 200];
  const int b = blockIdx.y;
  const int row0 = blockIdx.x * 64;
  const int tid = threadIdx.x;
  const int w = tid >> 6, lane = tid & 63;
  const int ln = lane & 15, mq = lane >> 4;
  const int rbase = row0 + w * 16;

  u16x8 afr[6];
#pragma unroll
  for (int kc = 0; kc < 6; ++kc)
    afr[kc] = ld8bf(Tk + ((size_t)b * C_ + rbase + ln) * C_ + kc * 32 + mq * 8);

  stage_f32_bf16(Wq, Ws, tid);
  __syncthreads();

  f32x4 acc[12];
#pragma unroll
  for (int j = 0; j < 12; ++j) acc[j] = (f32x4)0.0f;
#pragma unroll
  for (int kc = 0; kc < 6; ++kc)
#pragma unroll
    for (int ct = 0; ct < 12; ++ct)
      acc[ct] = mfma16(afr[kc], *(const u16x8*)&Ws[(ct * 16 + ln) * 200 + kc * 32 + mq * 8],
                       acc[ct]);

  float rkn[4], rqn[12];
#pragma unroll
  for (int r = 0; r < 4; ++r) rkn[r] = kn[b * 256 + rbase + mq * 4 + r];
#pragma unroll
  for (int ct = 0; ct < 12; ++ct) rqn[ct] = qn[b * 256 + ct * 16 + ln];

  float mx[4] = {-1e30f, -1e30f, -1e30f, -1e30f};
#pragma unroll
  for (int ct = 0; ct < 12; ++ct)
#pragma unroll
    for (int r = 0; r < 4; ++r) {
      float l = acc[ct][r] / (rkn[r] * rqn[ct]);
      acc[ct][r] = l;
      mx[r] = fmaxf(mx[r], l);
    }
#pragma unroll
  for (int m = 1; m < 16; m <<= 1)
#pragma unroll
    for (int r = 0; r < 4; ++r) mx[r] = fmaxf(mx[r], __shfl_xor(mx[r], m));
  float sm[4] = {0.f, 0.f, 0.f, 0.f};
#pragma unroll
  for (int ct = 0; ct < 12; ++ct)
#pragma unroll
    for (int r = 0; r < 4; ++r) {
      float e = expf(acc[ct][r] - mx[r]);
      acc[ct][r] = e;
      sm[r] += e;
    }
#pragma unroll
  for (int m = 1; m < 16; m <<= 1)
#pragma unroll
    for (int r = 0; r < 4; ++r) sm[r] += __shfl_xor(sm[r], m);
  float inv[4];
#pragma unroll
  for (int r = 0; r < 4; ++r) inv[r] = 1.f / sm[r];
#pragma unroll
  for (int ct = 0; ct < 12; ++ct)
#pragma unroll
    for (int r = 0; r < 4; ++r) {
      int lrow = w * 16 + mq * 4 + r;
      As[lrow * 200 + ct * 16 + ln] = f2bf(acc[ct][r] * inv[r]);
    }
  __syncthreads();                                 // QK reads of Ws done; As complete

  stage_f32_bf16(WvT, Ws, tid);                    // overwrite Ws with WvT
  __syncthreads();

  f32x4 tv[12];
#pragma unroll
  for (int j = 0; j < 12; ++j) tv[j] = (f32x4)0.0f;
#pragma unroll
  for (int kc = 0; kc < 6; ++kc) {
    u16x8 a2 = *(const u16x8*)&As[(w * 16 + ln) * 200 + kc * 32 + mq * 8];
#pragma unroll
    for (int ct = 0; ct < 12; ++ct)
      tv[ct] = mfma16(a2, *(const u16x8*)&Ws[(ct * 16 + ln) * 200 + kc * 32 + mq * 8],
                      tv[ct]);
  }
#pragma unroll
  for (int ct = 0; ct < 12; ++ct) {
    uint2 pk;
    pk.x = pkbf(tv[ct][0], tv[ct][1]);
    pk.y = pkbf(tv[ct][2], tv[ct][3]);
    *(uint2*)&Tvt[((size_t)b * C_ + ct * 16 + ln) * C_ + row0 + w * 16 + mq * 4] = pk;
  }
}

// K3: M = Wo2 · Tv. B = Tvt[b] (already bf16) staged to LDS. grid (3, B_).
__global__ __launch_bounds__(256, 2) void m2_kernel(
    const float* __restrict__ Wo2, const unsigned short* __restrict__ Tvt,
    float* __restrict__ Mw) {
  __shared__ __align__(16) unsigned short Ts2[192 * 200];
  const int b = blockIdx.y;
  const int row0 = blockIdx.x * 64;
  const int tid = threadIdx.x;
  const int w = tid >> 6, lane = tid & 63;
  const int ln = lane & 15, mq = lane >> 4;
  const int rbase = row0 + w * 16;

  u16x8 afr[6];
#pragma unroll
  for (int kc = 0; kc < 6; ++kc)
    afr[kc] = ld8bf(Wo2 + (size_t)(rbase + ln) * C_ + kc * 32 + mq * 8);

  stage_bf16(Tvt + (size_t)b * CC2, Ts2, tid);
  __syncthreads();

  f32x4 acc[12];
#pragma unroll
  for (int j = 0; j < 12; ++j) acc[j] = (f32x4)0.0f;
#pragma unroll
  for (int kc = 0; kc < 6; ++kc)
#pragma unroll
    for (int ct = 0; ct < 12; ++ct)
      acc[ct] = mfma16(afr[kc], *(const u16x8*)&Ts2[(ct * 16 + ln) * 200 + kc * 32 + mq * 8],
                       acc[ct]);
#pragma unroll
  for (int ct = 0; ct < 12; ++ct)
#pragma unroll
    for (int r = 0; r < 4; ++r)
      Mw[(size_t)b * CC2 + (rbase + mq * 4 + r) * C_ + ct * 16 + ln] = acc[ct][r];
}

// ---------------- final: out[b] = M[b] @ X[b] + bias2, bf16 MFMA ----------------
// v3b (measured 59.4 us): 64-px blocks, 24 KB LDS, 2-section register-prefetch,
// packed b64 LDS writes, swizzle key (p>>1)&7, __launch_bounds__(384,4) (no spill).
__global__ __launch_bounds__(384, 4) void final3_kernel(const float* __restrict__ xin,
                                                        const float* __restrict__ Mw,
                                                        const float* __restrict__ bias2,
                                                        float* __restrict__ out) {
  const int b = blockIdx.y;
  const int p0 = blockIdx.x * 64;
  __shared__ __align__(16) unsigned short Ts[64 * 192];   // 24 KB swizzled [p][c]
  const int tid = threadIdx.x;
  const int wv = tid >> 6;                         // 0..5, wave owns rows 32*wv..+31
  const int lane = tid & 63;
  const int ln = lane & 15, mq = lane >> 4;
  const float* Mb = Mw + (size_t)b * CC2;

  // staging map: c-quad c0 = (tid>>3)*4 (48 quads), px-quad pq = tid&7 (8 per section)
  const int c0 = (tid >> 3) * 4;
  const int pq = tid & 7;
  const float* xsrc = xin + ((size_t)b * C_ + c0) * N_ + p0 + pq * 4;

  float4 ldA[4], ldB[4];
#pragma unroll
  for (int l = 0; l < 4; ++l) ldA[l] = *(const float4*)(xsrc + (size_t)l * N_);

  // M fragments (bf16) + bias, loaded once per block
  u16x8 afr[6][2];
  float bo[2][4];
#pragma unroll
  for (int i = 0; i < 2; ++i) {
    int row = 32 * wv + 16 * i + ln;
#pragma unroll
    for (int kc = 0; kc < 6; ++kc)
      afr[kc][i] = ld8bf(Mb + row * C_ + kc * 32 + mq * 8);
#pragma unroll
    for (int r = 0; r < 4; ++r) bo[i][r] = bias2[32 * wv + 16 * i + mq * 4 + r];
  }

  auto stage_write = [&](const float4* ld, int sbase) {
#pragma unroll
    for (int e = 0; e < 4; ++e) {                  // e compile-time: direct .x/.y/.z/.w
      int p = sbase + pq * 4 + e;
      int idx = p * 192 + ((((c0 >> 3) ^ ((p >> 1) & 7)) << 3) | (c0 & 7));
      uint2 pk;
      pk.x = pkbf(f4get(ld[0], e), f4get(ld[1], e));
      pk.y = pkbf(f4get(ld[2], e), f4get(ld[3], e));
      *(uint2*)&Ts[idx] = pk;                      // ds_write_b64
    }
  };

  auto compute = [&](int pt) {
    const int p = pt * 16 + ln;
    const int pkey = (p >> 1) & 7;
    f32x4 acc0 = (f32x4)0.0f, acc1 = (f32x4)0.0f;
#pragma unroll
    for (int kc = 0; kc < 6; ++kc) {
      u16x8 bf = *(const u16x8*)&Ts[p * 192 + (((kc * 4 + mq) ^ pkey) << 3)];
      acc0 = mfma16(afr[kc][0], bf, acc0);
      acc1 = mfma16(afr[kc][1], bf, acc1);
    }
    const int pp = p0 + p;
#pragma unroll
    for (int r = 0; r < 4; ++r) {
      int row0 = 32 * wv + mq * 4 + r;
      out[((size_t)b * C_ + row0) * N_ + pp] = acc0[r] + bo[0][r];
      out[((size_t)b * C_ + row0 + 16) * N_ + pp] = acc1[r] + bo[1][r];
    }
  };

  stage_write(ldA, 0);
  __syncthreads();
#pragma unroll
  for (int l = 0; l < 4; ++l) ldB[l] = *(const float4*)(xsrc + 32 + (size_t)l * N_);
  compute(0);
  compute(1);
  stage_write(ldB, 32);                            // waits vmcnt here, after MFMA
  __syncthreads();
  compute(2);
  compute(3);
}

extern "C" void kernel_launch(void* const* d_in, const int* in_sizes, int n_in,
                              void* d_out, int out_size, void* d_ws, size_t ws_size,
                              hipStream_t stream) {
  const float* xin    = (const float*)d_in[0];
  const float* wsplit = (const float*)d_in[1];
  const float* wq     = (const float*)d_in[2];
  const float* wk     = (const float*)d_in[3];
  const float* wv     = (const float*)d_in[4];
  const float* wproj  = (const float*)d_in[5];
  const float* bproj  = (const float*)d_in[6];
  const float* wout   = (const float*)d_in[7];
  float* out = (float*)d_out;

  float* ws = (float*)d_ws;
  float* G     = ws;                         // B*CC2
  float* Wq    = G + (size_t)B_ * CC2;       // CC2
  float* WvT   = Wq + CC2;
  float* Wk    = WvT + CC2;
  float* Wv    = Wk + CC2;
  float* Wo2   = Wv + CC2;
  float* bias2 = Wo2 + CC2;                  // 256
  float* Tk    = bias2 + 256;                // B*CC2
  float* Tvt_f = Tk + (size_t)B_ * CC2;      // B*CC2 (bf16 packed, half used)
  float* Mw    = Tvt_f + (size_t)B_ * CC2;
  float* qn    = Mw + (size_t)B_ * CC2;      // 256*B
  float* kn    = qn + 256 * B_;              // 256*B
  float* P     = kn + 256 * B_;              // B*NCHUNK*CC2 (37.7 MB) if it fits

  size_t base_floats = (size_t)(P - ws);
  size_t need_bytes = (base_floats + (size_t)B_ * NCHUNK * CC2) * sizeof(float);
  bool use_partials = ws_size >= need_bytes;

  fold_kernel<<<(4 * CC2 + 255) / 256, 256, 0, stream>>>(
      wsplit, wq, wk, wv, wproj, bproj, wout, Wq, WvT, Wk, Wv, Wo2, bias2);
  if (use_partials) {
    gram3_kernel<false><<<dim3(NCHUNK, 2, B_), 384, 0, stream>>>(xin, P);
    gsum_kernel<<<dim3(CC2 / 1024, B_), 256, 0, stream>>>(P, G);
  } else {
    hipMemsetAsync(G, 0, (size_t)B_ * CC2 * sizeof(float), stream);
    gram3_kernel<true><<<dim3(NCHUNK, 2, B_), 384, 0, stream>>>(xin, G);
  }
  tkqn2_kernel<<<dim3(6, B_), 256, 0, stream>>>(Wk, Wq, G, Tk, kn, qn);
  attn2_kernel<<<dim3(3, B_), 256, 0, stream>>>(Tk, Wq, WvT, kn, qn,
                                                (unsigned short*)Tvt_f);
  m2_kernel<<<dim3(3, B_), 256, 0, stream>>>(Wo2, (const unsigned short*)Tvt_f, Mw);
  final3_kernel<<<dim3(N_ / 64, B_), 384, 0, stream>>>(xin, Mw, bias2, out);
}